// Round 12
// baseline (194.593 us; speedup 1.0000x reference)
//
#include <hip/hip_runtime.h>
#include <hip/hip_bf16.h>

// B=32, S=2048, D=1024, C=256
//   top[b,s] = max_c sum_d (latent[c,d]*att_diag[d]) * (tm*embeds[b,s,d] + pos_table[rel+64,d])
//   p = softmax_s(top*m + (m-1)*NEG);  ctx[b,d] = tok_diag[d] * sum_s embeds*p
//
// R12: occupancy round. 512-thr / 8-wave / 128-token blocks; wave (cg,tg)
// owns 8 c-tiles x 2 token-sets -> acc = 64 VGPR -> 16 waves/CU (4/SIMD),
// 2 blocks/CU. 2-term split-fp16 MFMA (W_hi*(e_hi+e_lo), absmax ~0.06).
// W_hi staged via global_load_lds (16KB/kc, dbuf 32KB); counted-vmcnt
// barrier (stage=2 + e=4 outstanding -> vmcnt(4)); p read direct from L2.
// Flash epilogue: per-block (M_b, Z_b, P); k_finish combines.
//
// ws: whi 512K | partial 2M | mblk 2K | zblk 2K

#define HC 64
#define NEGV 1000000000000.0f

constexpr int Bb = 32, Ss = 2048, Dd = 1024, Cc = 256;
constexpr int NKC = 32;                 // k-chunks of 32
constexpr int NBLK = 16;                // 128-token blocks per batch

typedef _Float16 f16x8 __attribute__((ext_vector_type(8)));
typedef float    f32x4 __attribute__((ext_vector_type(4)));
typedef float    f32x2 __attribute__((ext_vector_type(2)));

// ---------------- Pass 0: W_hi -> per-kc fragment chunks ----------
// layout: whi[kc][ct][lane][8] (16KB/kc)
// A-frag map: lane = (c%16) + 16*g holds A[c][k = kc*32 + 8g + i]
__global__ __launch_bounds__(256) void k_prep_w(
    const float* __restrict__ latent, const float* __restrict__ att_diag,
    _Float16* __restrict__ whi)
{
    const int idx = blockIdx.x * 256 + threadIdx.x;   // c*Dd + k
    const int c = idx >> 10, k = idx & 1023;
    const float wv = latent[idx] * att_diag[k];
    const int kc = k >> 5, g = (k >> 3) & 3, i = k & 7;
    const int lane = (c & 15) + 16 * g, ct = c >> 4;
    whi[(size_t)kc * 8192 + (size_t)ct * 512 + lane * 8 + i] = (_Float16)wv;
}

// ------- Pass 1: scores via MFMA, block max/sumexp, flash ctx partial -----
__global__ __launch_bounds__(512, 4) void k_scores_mfma(
    const float* __restrict__ embeds,    // [B][S][D]
    const float* __restrict__ mask,      // [B][S]
    const float* __restrict__ pos_table, // [132][D]
    const float* __restrict__ tok_mult,  // [1]
    const int*   __restrict__ rel_ids,   // [B][S]
    const _Float16* __restrict__ whi,    // [NKC][16][64][8]
    float* __restrict__ partial,         // [B][NBLK][D]
    float* __restrict__ mblk,            // [B][NBLK]
    float* __restrict__ zblk)            // [B][NBLK]
{
    __shared__ _Float16 sbuf[2][8192];   // 2 x 16KB (W_hi chunks)
    __shared__ float red[2][128];        // per-c-half token maxes
    __shared__ float w_sh[128];
    __shared__ float red2[2], zred[2];

    const int t  = threadIdx.x;
    const int wvid = t >> 6;    // wave 0..7
    const int cg = wvid & 1;    // c-half: ct in [8cg, 8cg+8)
    const int tg = wvid >> 1;   // token quarter 0..3
    const int l  = t & 63;
    const int lr = l & 15;      // token within set / output col
    const int lg = l >> 4;      // k-group

    const int b   = blockIdx.x >> 4;     // 16 blocks of 128 tokens per batch
    const int blk = blockIdx.x & 15;
    const int s0  = blk * 128;

    const float tm = tok_mult[0];

    const float* erow[2];
    const float* prow[2];
    #pragma unroll
    for (int st = 0; st < 2; st++) {
        const int tok = s0 + tg * 32 + st * 16 + lr;
        erow[st] = embeds + ((size_t)b * Ss + tok) * Dd;
        prow[st] = pos_table + (size_t)(rel_ids[b * Ss + tok] + HC) * Dd;
    }

    f32x4 acc[8][2];   // [ct-in-half][set]
    #pragma unroll
    for (int j = 0; j < 8; j++)
        #pragma unroll
        for (int st = 0; st < 2; st++) acc[j][st] = (f32x4){0.f, 0.f, 0.f, 0.f};

    // e prefetch (one kc ahead): 4 loads
    f32x4 e0[2], e1[2];
    auto loadE = [&](int kc) {
        const int k0 = kc * 32 + lg * 8;
        #pragma unroll
        for (int st = 0; st < 2; st++) {
            e0[st] = *(const f32x4*)(erow[st] + k0);
            e1[st] = *(const f32x4*)(erow[st] + k0 + 4);
        }
    };

    // stage one 16KB W_hi chunk: 16 x 1KB chunks over 8 waves (2 per wave)
    auto stage = [&](int kc, _Float16* dst) {
        const _Float16* src = whi + (size_t)kc * 8192;
        #pragma unroll
        for (int i = 0; i < 2; i++) {
            const int off = (i * 8 + wvid) << 9;
            __builtin_amdgcn_global_load_lds(
                (const __attribute__((address_space(1))) void*)(src + off + l * 8),
                (__attribute__((address_space(3))) void*)(dst + off),
                16, 0, 0);
        }
    };

    // prologue: stage first (oldest), then e
    stage(0, sbuf[0]);
    loadE(0);
    asm volatile("s_waitcnt vmcnt(4)" ::: "memory");  // stage(0) landed
    __builtin_amdgcn_s_barrier();

    int cur = 0;
    for (int kc = 0; kc < NKC; kc++) {
        const int k0 = kc * 32 + lg * 8;
        const _Float16* base = sbuf[cur] + (cg * 8) * 512 + l * 8;

        // ---- set 0: build frags (consumes e(kc) set0 + p direct), MFMA ----
        {
            const f32x4 pa = *(const f32x4*)(prow[0] + k0);
            const f32x4 pb = *(const f32x4*)(prow[0] + k0 + 4);
            float e[8], p[8];
            *(f32x4*)&e[0] = e0[0]; *(f32x4*)&e[4] = e1[0];
            *(f32x4*)&p[0] = pa;    *(f32x4*)&p[4] = pb;
            f16x8 bh, bl;
            #pragma unroll
            for (int i = 0; i < 8; i++) {
                const float x = fmaf(tm, e[i], p[i]);
                const _Float16 h = (_Float16)x;
                bh[i] = h;
                bl[i] = (_Float16)(x - (float)h);
            }
            if (kc + 1 < NKC) stage(kc + 1, sbuf[cur ^ 1]);  // 2 loads (oldest at barrier)
            #pragma unroll
            for (int j = 0; j < 8; j++) {
                const f16x8 ah = *(const f16x8*)(base + j * 512);
                acc[j][0] = __builtin_amdgcn_mfma_f32_16x16x32_f16(ah, bh, acc[j][0], 0, 0, 0);
                acc[j][0] = __builtin_amdgcn_mfma_f32_16x16x32_f16(ah, bl, acc[j][0], 0, 0, 0);
            }
        }
        // ---- set 1: build frags, then prefetch e(kc+1), MFMA ----
        {
            const f32x4 pa = *(const f32x4*)(prow[1] + k0);
            const f32x4 pb = *(const f32x4*)(prow[1] + k0 + 4);
            float e[8], p[8];
            *(f32x4*)&e[0] = e0[1]; *(f32x4*)&e[4] = e1[1];
            *(f32x4*)&p[0] = pa;    *(f32x4*)&p[4] = pb;
            f16x8 bh, bl;
            #pragma unroll
            for (int i = 0; i < 8; i++) {
                const float x = fmaf(tm, e[i], p[i]);
                const _Float16 h = (_Float16)x;
                bh[i] = h;
                bl[i] = (_Float16)(x - (float)h);
            }
            if (kc + 1 < NKC) loadE(kc + 1);   // 4 HBM loads; stay in flight past barrier
            #pragma unroll
            for (int j = 0; j < 8; j++) {
                const f16x8 ah = *(const f16x8*)(base + j * 512);
                acc[j][1] = __builtin_amdgcn_mfma_f32_16x16x32_f16(ah, bh, acc[j][1], 0, 0, 0);
                acc[j][1] = __builtin_amdgcn_mfma_f32_16x16x32_f16(ah, bl, acc[j][1], 0, 0, 0);
            }
        }
        // wait only for this iter's 2 stage loads; e(kc+1) stays in flight
        asm volatile("s_waitcnt vmcnt(4)" ::: "memory");
        __builtin_amdgcn_s_barrier();
        cur ^= 1;
    }

    // per-token max over this wave's 8 c-tiles (half of c), write to LDS
    #pragma unroll
    for (int st = 0; st < 2; st++) {
        float mx = acc[0][st][0];
        #pragma unroll
        for (int j = 0; j < 8; j++)
            #pragma unroll
            for (int r = 0; r < 4; r++) mx = fmaxf(mx, acc[j][st][r]);
        mx = fmaxf(mx, __shfl_xor(mx, 16));
        mx = fmaxf(mx, __shfl_xor(mx, 32));
        if (lg == 0) red[cg][tg * 32 + st * 16 + lr] = mx;
    }
    __syncthreads();

    // combine c-halves, mask -> token logit; block max M_b
    if (t < 128) {
        const int s = s0 + t;
        const float mk = mask[b * Ss + s];
        const float lv = fmaxf(red[0][t], red[1][t]) * mk + (mk - 1.0f) * NEGV;
        red[0][t] = lv;   // reuse as l_sh
        float v = lv;
        #pragma unroll
        for (int o = 32; o >= 1; o >>= 1) v = fmaxf(v, __shfl_xor(v, o));
        if ((t & 63) == 0) red2[t >> 6] = v;
    }
    __syncthreads();
    const float Mb = fmaxf(red2[0], red2[1]);
    if (t < 128) w_sh[t] = expf(red[0][t] - Mb);
    __syncthreads();
    if (t < 128) {
        float z = w_sh[t];
        #pragma unroll
        for (int o = 32; o >= 1; o >>= 1) z += __shfl_xor(z, o);
        if ((t & 63) == 0) zred[t >> 6] = z;
    }
    __syncthreads();

    // block-local ctx partial: P[d] = sum_s w_sh[s] * e[s0+s][d]  (L2-hot)
    {
        const float* eb = embeds + ((size_t)b * Ss + s0) * Dd + t * 2;
        f32x2 ca = (f32x2){0.f, 0.f};
        #pragma unroll 8
        for (int s = 0; s < 128; s++) {
            const float wgt = w_sh[s];
            const f32x2 ev = *(const f32x2*)(eb + (size_t)s * Dd);
            ca[0] = fmaf(wgt, ev[0], ca[0]);
            ca[1] = fmaf(wgt, ev[1], ca[1]);
        }
        *(f32x2*)(partial + ((size_t)(b * NBLK + blk)) * Dd + t * 2) = ca;
        if (t == 0) {
            mblk[b * NBLK + blk] = Mb;
            zblk[b * NBLK + blk] = zred[0] + zred[1];
        }
    }
}

// ------- Pass 2: global flash combine + tok_diag -------
__global__ __launch_bounds__(256) void k_finish(
    const float* __restrict__ mblk, const float* __restrict__ zblk,
    const float* __restrict__ partial, const float* __restrict__ tok_diag,
    float* __restrict__ out)
{
    __shared__ float cf[NBLK];
    const int b = blockIdx.x, t = threadIdx.x;

    if (t < 64) {
        const float mv = (t < NBLK) ? mblk[b * NBLK + t] : -3.4e38f;
        float M = mv;
        #pragma unroll
        for (int o = 32; o >= 1; o >>= 1) M = fmaxf(M, __shfl_xor(M, o));
        const float zv = (t < NBLK) ? zblk[b * NBLK + t] * expf(mv - M) : 0.f;
        float Z = zv;
        #pragma unroll
        for (int o = 32; o >= 1; o >>= 1) Z += __shfl_xor(Z, o);
        if (t < NBLK) cf[t] = expf(mv - M) / Z;
    }
    __syncthreads();

    const int d = t * 4;
    f32x4 a = (f32x4){0.f, 0.f, 0.f, 0.f};
    #pragma unroll
    for (int j = 0; j < NBLK; j++) {
        const float c = cf[j];
        const f32x4 p = *(const f32x4*)(partial + ((size_t)(b * NBLK + j)) * Dd + d);
        a[0] = fmaf(c, p[0], a[0]);
        a[1] = fmaf(c, p[1], a[1]);
        a[2] = fmaf(c, p[2], a[2]);
        a[3] = fmaf(c, p[3], a[3]);
    }
    const f32x4 td = *(const f32x4*)(tok_diag + d);
    f32x4 o = a * td;
    *(f32x4*)(out + (size_t)b * Dd + d) = o;
}

extern "C" void kernel_launch(void* const* d_in, const int* in_sizes, int n_in,
                              void* d_out, int out_size, void* d_ws, size_t ws_size,
                              hipStream_t stream) {
    const float* embeds    = (const float*)d_in[0];
    const float* mask      = (const float*)d_in[1];
    const float* latent    = (const float*)d_in[2];
    const float* att_diag  = (const float*)d_in[3];
    const float* tok_diag  = (const float*)d_in[4];
    const float* pos_table = (const float*)d_in[5];
    const float* tok_mult  = (const float*)d_in[6];
    const int*   rel_ids   = (const int*)d_in[7];
    float* out = (float*)d_out;

    char* ws = (char*)d_ws;
    _Float16* whi    = (_Float16*)(ws);              // 512 KB
    float*    partial= (float*)(ws + 524288);        // 2 MB
    float*    mblk   = (float*)(ws + 2621440);       // 2 KB
    float*    zblk   = (float*)(ws + 2623488);       // 2 KB

    k_prep_w<<<(Cc * Dd) / 256, 256, 0, stream>>>(latent, att_diag, whi);
    k_scores_mfma<<<Bb * NBLK, 512, 0, stream>>>(
        embeds, mask, pos_table, tok_mult, rel_ids, whi, partial, mblk, zblk);
    k_finish<<<Bb, 256, 0, stream>>>(mblk, zblk, partial, tok_diag, out);
}

// Round 13
// 164.555 us; speedup vs baseline: 1.1825x; 1.1825x over previous
//
#include <hip/hip_runtime.h>
#include <hip/hip_bf16.h>

// B=32, S=2048, D=1024, C=256
//   top[b,s] = max_c sum_d (latent[c,d]*att_diag[d]) * (tm*embeds[b,s,d] + pos_table[rel+64,d])
//   p = softmax_s(top*m + (m-1)*NEG);  ctx[b,d] = tok_diag[d] * sum_s embeds*p
//
// R13: occupancy via GRID. 1024 blocks (64 tokens each) x 4 waves (256 thr);
// wave (cg,tg) owns 8 c-tiles x 2 token-sets -> acc=64 VGPR; launch_bounds
// (256,4) -> <=128 VGPR, 4 blocks/CU, 16 waves/CU. 2-term split-fp16 MFMA.
// W_hi staged via global_load_lds (16KB/kc, dbuf 32KB); counted-vmcnt
// barrier (4 stage waited, 4 e in flight); p read direct from L2 (TLP
// hides); both sets share ah frags (8 ds_read/kc/wave). Flash epilogue
// per 64-token block (M_b, Z_b, P); k_finish combines 32 partials.
//
// ws: whi 512K | partial 4M | mblk 4K | zblk 4K

#define HC 64
#define NEGV 1000000000000.0f

constexpr int Bb = 32, Ss = 2048, Dd = 1024, Cc = 256;
constexpr int NKC = 32;                 // k-chunks of 32
constexpr int NBLK = 32;                // 64-token blocks per batch

typedef _Float16 f16x8 __attribute__((ext_vector_type(8)));
typedef float    f32x4 __attribute__((ext_vector_type(4)));

// ---------------- Pass 0: W_hi -> per-kc fragment chunks ----------
// layout: whi[kc][ct][lane][8] (16KB/kc)
// A-frag map: lane = (c%16) + 16*g holds A[c][k = kc*32 + 8g + i]
__global__ __launch_bounds__(256) void k_prep_w(
    const float* __restrict__ latent, const float* __restrict__ att_diag,
    _Float16* __restrict__ whi)
{
    const int idx = blockIdx.x * 256 + threadIdx.x;   // c*Dd + k
    const int c = idx >> 10, k = idx & 1023;
    const float wv = latent[idx] * att_diag[k];
    const int kc = k >> 5, g = (k >> 3) & 3, i = k & 7;
    const int lane = (c & 15) + 16 * g, ct = c >> 4;
    whi[(size_t)kc * 8192 + (size_t)ct * 512 + lane * 8 + i] = (_Float16)wv;
}

// ------- Pass 1: scores via MFMA, block max/sumexp, flash ctx partial -----
__global__ __launch_bounds__(256, 4) void k_scores_mfma(
    const float* __restrict__ embeds,    // [B][S][D]
    const float* __restrict__ mask,      // [B][S]
    const float* __restrict__ pos_table, // [132][D]
    const float* __restrict__ tok_mult,  // [1]
    const int*   __restrict__ rel_ids,   // [B][S]
    const _Float16* __restrict__ whi,    // [NKC][16][64][8]
    float* __restrict__ partial,         // [B][NBLK][D]
    float* __restrict__ mblk,            // [B][NBLK]
    float* __restrict__ zblk)            // [B][NBLK]
{
    __shared__ _Float16 sbuf[2][8192];   // 2 x 16KB (W_hi chunks)
    __shared__ float red[2][64];         // per-c-half token maxes
    __shared__ float w_sh[64];

    const int t  = threadIdx.x;
    const int wvid = t >> 6;    // wave 0..3
    const int cg = wvid & 1;    // c-half: ct in [8cg, 8cg+8)
    const int tg = wvid >> 1;   // token half 0..1
    const int l  = t & 63;
    const int lr = l & 15;      // token within set / output col
    const int lg = l >> 4;      // k-group

    const int b   = blockIdx.x >> 5;     // 32 blocks of 64 tokens per batch
    const int blk = blockIdx.x & 31;
    const int s0  = blk * 64;

    const float tm = tok_mult[0];

    const float* erow[2];
    const float* prow[2];
    #pragma unroll
    for (int st = 0; st < 2; st++) {
        const int tok = s0 + tg * 32 + st * 16 + lr;
        erow[st] = embeds + ((size_t)b * Ss + tok) * Dd;
        prow[st] = pos_table + (size_t)(rel_ids[b * Ss + tok] + HC) * Dd;
    }

    f32x4 acc[8][2];   // [ct-in-half][set]
    #pragma unroll
    for (int j = 0; j < 8; j++)
        #pragma unroll
        for (int st = 0; st < 2; st++) acc[j][st] = (f32x4){0.f, 0.f, 0.f, 0.f};

    // e prefetch (one kc ahead): 4 loads, 16 VGPR
    f32x4 e0[2], e1[2];
    auto loadE = [&](int kc) {
        const int k0 = kc * 32 + lg * 8;
        #pragma unroll
        for (int st = 0; st < 2; st++) {
            e0[st] = *(const f32x4*)(erow[st] + k0);
            e1[st] = *(const f32x4*)(erow[st] + k0 + 4);
        }
    };

    // stage one 16KB W_hi chunk: 16 x 1KB chunks over 4 waves (4 per wave)
    auto stage = [&](int kc, _Float16* dst) {
        const _Float16* src = whi + (size_t)kc * 8192;
        #pragma unroll
        for (int i = 0; i < 4; i++) {
            const int off = (i * 4 + wvid) << 9;
            __builtin_amdgcn_global_load_lds(
                (const __attribute__((address_space(1))) void*)(src + off + l * 8),
                (__attribute__((address_space(3))) void*)(dst + off),
                16, 0, 0);
        }
    };

    // prologue: stage first (oldest), then e
    stage(0, sbuf[0]);
    loadE(0);
    asm volatile("s_waitcnt vmcnt(4)" ::: "memory");  // stage(0) landed
    __builtin_amdgcn_s_barrier();

    int cur = 0;
    for (int kc = 0; kc < NKC; kc++) {
        if (kc + 1 < NKC) stage(kc + 1, sbuf[cur ^ 1]);   // 4 loads (oldest)

        const int k0 = kc * 32 + lg * 8;
        // build both sets' B frags (p direct from L2; e from prefetch regs)
        f16x8 bh[2], bl[2];
        #pragma unroll
        for (int st = 0; st < 2; st++) {
            const f32x4 pa = *(const f32x4*)(prow[st] + k0);
            const f32x4 pb = *(const f32x4*)(prow[st] + k0 + 4);
            float e[8], p[8];
            *(f32x4*)&e[0] = e0[st]; *(f32x4*)&e[4] = e1[st];
            *(f32x4*)&p[0] = pa;     *(f32x4*)&p[4] = pb;
            #pragma unroll
            for (int i = 0; i < 8; i++) {
                const float x = fmaf(tm, e[i], p[i]);
                const _Float16 h = (_Float16)x;
                bh[st][i] = h;
                bl[st][i] = (_Float16)(x - (float)h);
            }
        }
        if (kc + 1 < NKC) loadE(kc + 1);   // 4 HBM loads; in flight past barrier

        const _Float16* base = sbuf[cur] + (cg * 8) * 512 + l * 8;
        #pragma unroll
        for (int j = 0; j < 8; j++) {
            const f16x8 ah = *(const f16x8*)(base + j * 512);   // shared by both sets
            #pragma unroll
            for (int st = 0; st < 2; st++) {
                acc[j][st] = __builtin_amdgcn_mfma_f32_16x16x32_f16(ah, bh[st], acc[j][st], 0, 0, 0);
                acc[j][st] = __builtin_amdgcn_mfma_f32_16x16x32_f16(ah, bl[st], acc[j][st], 0, 0, 0);
            }
        }
        // wait only for this iter's 4 stage loads; e(kc+1) stays in flight
        asm volatile("s_waitcnt vmcnt(4)" ::: "memory");
        __builtin_amdgcn_s_barrier();
        cur ^= 1;
    }

    // per-token max over this wave's 8 c-tiles -> LDS (c-half lanes)
    #pragma unroll
    for (int st = 0; st < 2; st++) {
        float mx = acc[0][st][0];
        #pragma unroll
        for (int j = 0; j < 8; j++)
            #pragma unroll
            for (int r = 0; r < 4; r++) mx = fmaxf(mx, acc[j][st][r]);
        mx = fmaxf(mx, __shfl_xor(mx, 16));
        mx = fmaxf(mx, __shfl_xor(mx, 32));
        if (lg == 0) red[cg][tg * 32 + st * 16 + lr] = mx;
    }
    __syncthreads();

    // wave 0: combine c-halves, mask, block max/sumexp (64 logits = 1 wave)
    if (t < 64) {
        const int s = s0 + t;
        const float mk = mask[b * Ss + s];
        const float lv = fmaxf(red[0][t], red[1][t]) * mk + (mk - 1.0f) * NEGV;
        float M = lv;
        #pragma unroll
        for (int o = 32; o >= 1; o >>= 1) M = fmaxf(M, __shfl_xor(M, o));
        const float wgt = expf(lv - M);
        w_sh[t] = wgt;
        float Z = wgt;
        #pragma unroll
        for (int o = 32; o >= 1; o >>= 1) Z += __shfl_xor(Z, o);
        if (t == 0) {
            mblk[b * NBLK + blk] = M;
            zblk[b * NBLK + blk] = Z;
        }
    }
    __syncthreads();

    // block-local ctx partial: P[d] = sum_s w_sh[s] * e[s0+s][d]  (L2-hot)
    {
        const float* eb = embeds + ((size_t)b * Ss + s0) * Dd + t * 4;
        f32x4 ca = (f32x4){0.f, 0.f, 0.f, 0.f};
        #pragma unroll 8
        for (int s = 0; s < 64; s++) {
            const float wgt = w_sh[s];
            const f32x4 ev = *(const f32x4*)(eb + (size_t)s * Dd);
            ca[0] = fmaf(wgt, ev[0], ca[0]);
            ca[1] = fmaf(wgt, ev[1], ca[1]);
            ca[2] = fmaf(wgt, ev[2], ca[2]);
            ca[3] = fmaf(wgt, ev[3], ca[3]);
        }
        *(f32x4*)(partial + ((size_t)(b * NBLK + blk)) * Dd + t * 4) = ca;
    }
}

// ------- Pass 2: global flash combine + tok_diag -------
__global__ __launch_bounds__(256) void k_finish(
    const float* __restrict__ mblk, const float* __restrict__ zblk,
    const float* __restrict__ partial, const float* __restrict__ tok_diag,
    float* __restrict__ out)
{
    __shared__ float cf[NBLK];
    const int b = blockIdx.x, t = threadIdx.x;

    if (t < 64) {
        const float mv = (t < NBLK) ? mblk[b * NBLK + t] : -3.4e38f;
        float M = mv;
        #pragma unroll
        for (int o = 32; o >= 1; o >>= 1) M = fmaxf(M, __shfl_xor(M, o));
        const float zv = (t < NBLK) ? zblk[b * NBLK + t] * expf(mv - M) : 0.f;
        float Z = zv;
        #pragma unroll
        for (int o = 32; o >= 1; o >>= 1) Z += __shfl_xor(Z, o);
        if (t < NBLK) cf[t] = expf(mv - M) / Z;
    }
    __syncthreads();

    const int d = t * 4;
    f32x4 a = (f32x4){0.f, 0.f, 0.f, 0.f};
    #pragma unroll
    for (int j = 0; j < NBLK; j++) {
        const float c = cf[j];
        const f32x4 p = *(const f32x4*)(partial + ((size_t)(b * NBLK + j)) * Dd + d);
        a[0] = fmaf(c, p[0], a[0]);
        a[1] = fmaf(c, p[1], a[1]);
        a[2] = fmaf(c, p[2], a[2]);
        a[3] = fmaf(c, p[3], a[3]);
    }
    const f32x4 td = *(const f32x4*)(tok_diag + d);
    f32x4 o = a * td;
    *(f32x4*)(out + (size_t)b * Dd + d) = o;
}

extern "C" void kernel_launch(void* const* d_in, const int* in_sizes, int n_in,
                              void* d_out, int out_size, void* d_ws, size_t ws_size,
                              hipStream_t stream) {
    const float* embeds    = (const float*)d_in[0];
    const float* mask      = (const float*)d_in[1];
    const float* latent    = (const float*)d_in[2];
    const float* att_diag  = (const float*)d_in[3];
    const float* tok_diag  = (const float*)d_in[4];
    const float* pos_table = (const float*)d_in[5];
    const float* tok_mult  = (const float*)d_in[6];
    const int*   rel_ids   = (const int*)d_in[7];
    float* out = (float*)d_out;

    char* ws = (char*)d_ws;
    _Float16* whi    = (_Float16*)(ws);              // 512 KB
    float*    partial= (float*)(ws + 524288);        // 4 MB
    float*    mblk   = (float*)(ws + 4718592);       // 4 KB
    float*    zblk   = (float*)(ws + 4722688);       // 4 KB

    k_prep_w<<<(Cc * Dd) / 256, 256, 0, stream>>>(latent, att_diag, whi);
    k_scores_mfma<<<Bb * NBLK, 256, 0, stream>>>(
        embeds, mask, pos_table, tok_mult, rel_ids, whi, partial, mblk, zblk);
    k_finish<<<Bb, 256, 0, stream>>>(mblk, zblk, partial, tok_diag, out);
}

// Round 14
// 123.028 us; speedup vs baseline: 1.5817x; 1.3375x over previous
//
#include <hip/hip_runtime.h>
#include <hip/hip_bf16.h>

// B=32, S=2048, D=1024, C=256
//   top[b,s] = max_c sum_d (latent[c,d]*att_diag[d]) * (tm*embeds[b,s,d] + pos_table[rel+64,d])
//   p = softmax_s(top*m + (m-1)*NEG);  ctx[b,d] = tok_diag[d] * sum_s embeds*p
//
// R14: 8-phase-style schedule on R11 geometry. 256 thr / 4 waves / 128 tok;
// wave owns 16 c-tiles x 2 token-sets; 2-term split-fp16 MFMA (W_hi*(e_hi+e_lo)).
// BK=64: stage 2 kc (32KB) per outer step into dbuf LDS (2x32KB); 4 sub-phases
// per step, each {4 ds_read + 16 MFMA}x2 with setprio around MFMA + s_barrier;
// stage at S0, e/p prefetch split S1/S2; ONE counted vmcnt(16) per step (only
// stage loads waited; 16 e/p loads span the barrier).
// Flash epilogue per 128-token block (M_b, Z_b, P); k_finish combines.
//
// ws: whi 512K | partial 2M | mblk 2K | zblk 2K

#define HC 64
#define NEGV 1000000000000.0f

constexpr int Bb = 32, Ss = 2048, Dd = 1024, Cc = 256;
constexpr int NKC = 32;                 // k-chunks of 32
constexpr int CT = Cc / 16;             // 16 c-tiles
constexpr int NOUT = 16;                // outer steps (2 kc each)
constexpr int NBLK = 16;                // 128-token blocks per batch

typedef _Float16 f16x8 __attribute__((ext_vector_type(8)));
typedef float    f32x4 __attribute__((ext_vector_type(4)));

// ---------------- Pass 0: W_hi -> per-kc fragment chunks ----------
// layout: whi[kc][ct][lane][8] (16KB/kc)
// A-frag map: lane = (c%16) + 16*g holds A[c][k = kc*32 + 8g + i]
__global__ __launch_bounds__(256) void k_prep_w(
    const float* __restrict__ latent, const float* __restrict__ att_diag,
    _Float16* __restrict__ whi)
{
    const int idx = blockIdx.x * 256 + threadIdx.x;   // c*Dd + k
    const int c = idx >> 10, k = idx & 1023;
    const float wv = latent[idx] * att_diag[k];
    const int kc = k >> 5, g = (k >> 3) & 3, i = k & 7;
    const int lane = (c & 15) + 16 * g, ct = c >> 4;
    whi[(size_t)kc * 8192 + (size_t)ct * 512 + lane * 8 + i] = (_Float16)wv;
}

// ------- Pass 1: scores via MFMA, block max/sumexp, flash ctx partial -----
__global__ __launch_bounds__(256, 2) void k_scores_mfma(
    const float* __restrict__ embeds,    // [B][S][D]
    const float* __restrict__ mask,      // [B][S]
    const float* __restrict__ pos_table, // [132][D]
    const float* __restrict__ tok_mult,  // [1]
    const int*   __restrict__ rel_ids,   // [B][S]
    const _Float16* __restrict__ whi,    // [NKC][CT][64][8]
    float* __restrict__ partial,         // [B][NBLK][D]
    float* __restrict__ mblk,            // [B][NBLK]
    float* __restrict__ zblk)            // [B][NBLK]
{
    __shared__ _Float16 sbuf[2][16384];  // 2 x 32KB (2 kc per buffer)
    __shared__ float l_sh[128];
    __shared__ float w_sh[128];
    __shared__ float red2[2], zred[2];

    const int t  = threadIdx.x;
    const int wv = t >> 6;      // wave 0..3
    const int l  = t & 63;
    const int lr = l & 15;      // token within set / output col
    const int lg = l >> 4;      // k-group

    const int b   = blockIdx.x >> 4;     // 16 blocks of 128 tokens per batch
    const int blk = blockIdx.x & 15;
    const int s0  = blk * 128;

    const float tm = tok_mult[0];

    const float* erow[2];
    const float* prow[2];
    #pragma unroll
    for (int st = 0; st < 2; st++) {
        const int tok = s0 + wv * 32 + st * 16 + lr;
        erow[st] = embeds + ((size_t)b * Ss + tok) * Dd;
        prow[st] = pos_table + (size_t)(rel_ids[b * Ss + tok] + HC) * Dd;
    }

    f32x4 acc[CT][2];
    #pragma unroll
    for (int ct = 0; ct < CT; ct++)
        #pragma unroll
        for (int st = 0; st < 2; st++) acc[ct][st] = (f32x4){0.f, 0.f, 0.f, 0.f};

    // e/p prefetch registers for the two kc halves of an outer step
    f32x4 eA0[2], eA1[2], pA0[2], pA1[2];   // kc half 0
    f32x4 eB0[2], eB1[2], pB0[2], pB1[2];   // kc half 1
    auto loadEP_A = [&](int out) {          // 8 loads
        const int k0 = out * 64 + lg * 8;
        #pragma unroll
        for (int st = 0; st < 2; st++) {
            eA0[st] = *(const f32x4*)(erow[st] + k0);
            eA1[st] = *(const f32x4*)(erow[st] + k0 + 4);
            pA0[st] = *(const f32x4*)(prow[st] + k0);
            pA1[st] = *(const f32x4*)(prow[st] + k0 + 4);
        }
    };
    auto loadEP_B = [&](int out) {          // 8 loads
        const int k0 = out * 64 + 32 + lg * 8;
        #pragma unroll
        for (int st = 0; st < 2; st++) {
            eB0[st] = *(const f32x4*)(erow[st] + k0);
            eB1[st] = *(const f32x4*)(erow[st] + k0 + 4);
            pB0[st] = *(const f32x4*)(prow[st] + k0);
            pB1[st] = *(const f32x4*)(prow[st] + k0 + 4);
        }
    };

    // stage one 32KB step-chunk (2 kc): 32 x 1KB chunks, 8 per wave
    auto stage = [&](int out, _Float16* dst) {
        const _Float16* src = whi + (size_t)out * 16384;
        #pragma unroll
        for (int i = 0; i < 8; i++) {
            const int off = (i * 4 + wv) << 9;
            __builtin_amdgcn_global_load_lds(
                (const __attribute__((address_space(1))) void*)(src + off + l * 8),
                (__attribute__((address_space(3))) void*)(dst + off),
                16, 0, 0);
        }
    };

    // build hi/lo fragments for one kc-half from its e/p regs
    auto build = [&](const f32x4* E0, const f32x4* E1, const f32x4* P0,
                     const f32x4* P1, f16x8* bh, f16x8* bl) {
        #pragma unroll
        for (int st = 0; st < 2; st++) {
            float e[8], p[8];
            *(f32x4*)&e[0] = E0[st]; *(f32x4*)&e[4] = E1[st];
            *(f32x4*)&p[0] = P0[st]; *(f32x4*)&p[4] = P1[st];
            #pragma unroll
            for (int i = 0; i < 8; i++) {
                const float x = fmaf(tm, e[i], p[i]);
                const _Float16 h = (_Float16)x;
                bh[st][i] = h;
                bl[st][i] = (_Float16)(x - (float)h);
            }
        }
    };

    // one sub-phase compute: 8 c-tiles of one kc-half -> 32 MFMA (2 mini-groups)
    auto quarter = [&](const _Float16* base, int ct0, const f16x8* bh, const f16x8* bl) {
        #pragma unroll
        for (int g4 = 0; g4 < 2; g4++) {
            f16x8 ah[4];
            #pragma unroll
            for (int j = 0; j < 4; j++)
                ah[j] = *(const f16x8*)(base + (ct0 + g4 * 4 + j) * 512 + l * 8);
            __builtin_amdgcn_s_setprio(1);
            #pragma unroll
            for (int j = 0; j < 4; j++) {
                const int ct = ct0 + g4 * 4 + j;
                #pragma unroll
                for (int st = 0; st < 2; st++) {
                    acc[ct][st] = __builtin_amdgcn_mfma_f32_16x16x32_f16(ah[j], bh[st], acc[ct][st], 0, 0, 0);
                    acc[ct][st] = __builtin_amdgcn_mfma_f32_16x16x32_f16(ah[j], bl[st], acc[ct][st], 0, 0, 0);
                }
            }
            __builtin_amdgcn_s_setprio(0);
        }
    };

    // prologue: stage(0) first (oldest), then e/p for both halves
    stage(0, sbuf[0]);
    loadEP_A(0);
    loadEP_B(0);
    asm volatile("s_waitcnt vmcnt(16)" ::: "memory");   // stage(0) landed
    __builtin_amdgcn_s_barrier();

    int cur = 0;
    for (int out = 0; out < NOUT; out++) {
        const bool more = (out + 1 < NOUT);
        const _Float16* base0 = sbuf[cur];          // kc half 0
        const _Float16* base1 = sbuf[cur] + 8192;   // kc half 1
        f16x8 bh0[2], bl0[2], bh1[2], bl1[2];

        // S0: stage next (8, oldest this step) | build kc0 | ct0-7 of kc0
        if (more) stage(out + 1, sbuf[cur ^ 1]);
        build(eA0, eA1, pA0, pA1, bh0, bl0);
        quarter(base0, 0, bh0, bl0);
        __builtin_amdgcn_s_barrier();

        // S1: prefetch next kc0 e/p (8) | ct8-15 of kc0
        if (more) loadEP_A(out + 1);
        quarter(base0, 8, bh0, bl0);
        __builtin_amdgcn_s_barrier();

        // S2: build kc1 | prefetch next kc1 e/p (8) | ct0-7 of kc1
        build(eB0, eB1, pB0, pB1, bh1, bl1);
        if (more) loadEP_B(out + 1);
        quarter(base1, 0, bh1, bl1);
        __builtin_amdgcn_s_barrier();

        // S3: ct8-15 of kc1 | counted wait: only the 8 stage loads must land
        quarter(base1, 8, bh1, bl1);
        asm volatile("s_waitcnt vmcnt(16)" ::: "memory");
        __builtin_amdgcn_s_barrier();
        cur ^= 1;
    }

    // masked logit per token -> LDS
    #pragma unroll
    for (int st = 0; st < 2; st++) {
        float mx = acc[0][st][0];
        #pragma unroll
        for (int ct = 0; ct < CT; ct++)
            #pragma unroll
            for (int r = 0; r < 4; r++) mx = fmaxf(mx, acc[ct][st][r]);
        mx = fmaxf(mx, __shfl_xor(mx, 16));
        mx = fmaxf(mx, __shfl_xor(mx, 32));
        if (lg == 0) {
            const int si = wv * 32 + st * 16 + lr;   // token within block
            const int s  = s0 + si;
            const float mk = mask[b * Ss + s];
            l_sh[si] = mx * mk + (mk - 1.0f) * NEGV;
        }
    }
    __syncthreads();

    // block max M_b over the 128 logits
    if (t < 128) {
        float v = l_sh[t];
        #pragma unroll
        for (int o = 32; o >= 1; o >>= 1) v = fmaxf(v, __shfl_xor(v, o));
        if ((t & 63) == 0) red2[t >> 6] = v;
    }
    __syncthreads();
    const float Mb = fmaxf(red2[0], red2[1]);
    if (t < 128) w_sh[t] = expf(l_sh[t] - Mb);
    __syncthreads();
    if (t < 128) {
        float z = w_sh[t];
        #pragma unroll
        for (int o = 32; o >= 1; o >>= 1) z += __shfl_xor(z, o);
        if ((t & 63) == 0) zred[t >> 6] = z;
    }
    __syncthreads();

    // block-local ctx partial: P[d] = sum_s w_sh[s] * e[s0+s][d]  (L2-hot)
    {
        const float* eb = embeds + ((size_t)b * Ss + s0) * Dd + t * 4;
        f32x4 ca = (f32x4){0.f, 0.f, 0.f, 0.f};
        #pragma unroll 8
        for (int s = 0; s < 128; s++) {
            const float wgt = w_sh[s];
            const f32x4 ev = *(const f32x4*)(eb + (size_t)s * Dd);
            ca[0] = fmaf(wgt, ev[0], ca[0]);
            ca[1] = fmaf(wgt, ev[1], ca[1]);
            ca[2] = fmaf(wgt, ev[2], ca[2]);
            ca[3] = fmaf(wgt, ev[3], ca[3]);
        }
        *(f32x4*)(partial + ((size_t)(b * NBLK + blk)) * Dd + t * 4) = ca;
        if (t == 0) {
            mblk[b * NBLK + blk] = Mb;
            zblk[b * NBLK + blk] = zred[0] + zred[1];
        }
    }
}

// ------- Pass 2: global flash combine + tok_diag -------
__global__ __launch_bounds__(256) void k_finish(
    const float* __restrict__ mblk, const float* __restrict__ zblk,
    const float* __restrict__ partial, const float* __restrict__ tok_diag,
    float* __restrict__ out)
{
    __shared__ float cf[NBLK];
    const int b = blockIdx.x, t = threadIdx.x;

    if (t < 64) {
        const float mv = (t < NBLK) ? mblk[b * NBLK + t] : -3.4e38f;
        float M = mv;
        #pragma unroll
        for (int o = 32; o >= 1; o >>= 1) M = fmaxf(M, __shfl_xor(M, o));
        const float zv = (t < NBLK) ? zblk[b * NBLK + t] * expf(mv - M) : 0.f;
        float Z = zv;
        #pragma unroll
        for (int o = 32; o >= 1; o >>= 1) Z += __shfl_xor(Z, o);
        if (t < NBLK) cf[t] = expf(mv - M) / Z;
    }
    __syncthreads();

    const int d = t * 4;
    f32x4 a = (f32x4){0.f, 0.f, 0.f, 0.f};
    #pragma unroll
    for (int j = 0; j < NBLK; j++) {
        const float c = cf[j];
        const f32x4 p = *(const f32x4*)(partial + ((size_t)(b * NBLK + j)) * Dd + d);
        a[0] = fmaf(c, p[0], a[0]);
        a[1] = fmaf(c, p[1], a[1]);
        a[2] = fmaf(c, p[2], a[2]);
        a[3] = fmaf(c, p[3], a[3]);
    }
    const f32x4 td = *(const f32x4*)(tok_diag + d);
    f32x4 o = a * td;
    *(f32x4*)(out + (size_t)b * Dd + d) = o;
}

extern "C" void kernel_launch(void* const* d_in, const int* in_sizes, int n_in,
                              void* d_out, int out_size, void* d_ws, size_t ws_size,
                              hipStream_t stream) {
    const float* embeds    = (const float*)d_in[0];
    const float* mask      = (const float*)d_in[1];
    const float* latent    = (const float*)d_in[2];
    const float* att_diag  = (const float*)d_in[3];
    const float* tok_diag  = (const float*)d_in[4];
    const float* pos_table = (const float*)d_in[5];
    const float* tok_mult  = (const float*)d_in[6];
    const int*   rel_ids   = (const int*)d_in[7];
    float* out = (float*)d_out;

    char* ws = (char*)d_ws;
    _Float16* whi    = (_Float16*)(ws);              // 512 KB
    float*    partial= (float*)(ws + 524288);        // 2 MB
    float*    mblk   = (float*)(ws + 2621440);       // 2 KB
    float*    zblk   = (float*)(ws + 2623488);       // 2 KB

    k_prep_w<<<(Cc * Dd) / 256, 256, 0, stream>>>(latent, att_diag, whi);
    k_scores_mfma<<<Bb * NBLK, 256, 0, stream>>>(
        embeds, mask, pos_table, tok_mult, rel_ids, whi, partial, mblk, zblk);
    k_finish<<<Bb, 256, 0, stream>>>(mblk, zblk, partial, tok_diag, out);
}